// Round 5
// baseline (8743.671 us; speedup 1.0000x reference)
//
#include <hip/hip_runtime.h>
#include <hip/hip_bf16.h>

// Feature dims fixed by the reference model architecture.
#define FACTOR   64
#define F2       128            // fused inv(64) + env(64) features
#define EMAX     8              // max supported env classes (reference: 4)

__device__ __forceinline__ float wsum(float x) {
#pragma unroll
    for (int o = 32; o > 0; o >>= 1) x += __shfl_xor(x, o, 64);
    return x;
}

// Zero cur1f [N*128] + curC [2B*128], set slots[N] to -1. Grid-stride.
__global__ void init_kernel(float4* __restrict__ cur1f, float4* __restrict__ curC,
                            int* __restrict__ slots, long n_cur1_f4, long n_curc_f4, int n_nodes) {
    long stride = (long)gridDim.x * blockDim.x;
    float4 z = {0.f, 0.f, 0.f, 0.f};
    for (long t = (long)blockIdx.x * blockDim.x + threadIdx.x; t < n_cur1_f4; t += stride)
        cur1f[t] = z;
    for (long t = (long)blockIdx.x * blockDim.x + threadIdx.x; t < n_curc_f4; t += stride)
        curC[t] = z;
    for (long t = (long)blockIdx.x * blockDim.x + threadIdx.x; t < n_nodes; t += stride)
        slots[(int)t] = -1;
}

// nodeToSlot: users_id[b] -> slot b, (U+items_id[b]) -> slot B+b.
// Duplicate nodes: any winner is fine (all readers use the same map entry).
__global__ void build_slots_kernel(const int* __restrict__ users, const int* __restrict__ items,
                                   int* __restrict__ slots, int B, int U) {
    int t = blockIdx.x * blockDim.x + threadIdx.x;
    if (t < B)            slots[users[t]] = t;
    else if (t < 2 * B)   slots[U + items[t - B]] = t;
}

// Layer 1 (dense): cur1[rows[e], :] += vals[e] * x0[cols[e], :]  for all e.
// x0 is the virtual [N,128] concat of (inv | env) layer-0 embeddings, gathered
// directly from the 4 input tables (f32).
// One wave per 64-edge chunk; lane L covers feature-pair L (float2).
__global__ void spmm1_kernel(const int* __restrict__ rows, const int* __restrict__ cols,
                             const float* __restrict__ vals,
                             const float* __restrict__ ui, const float* __restrict__ ii,
                             const float* __restrict__ ue, const float* __restrict__ ie,
                             float* __restrict__ dst, long nnz, int U) {
    long wid  = (long)(blockIdx.x * blockDim.x + threadIdx.x) >> 6;
    int lane = threadIdx.x & 63;
    long base = wid * 64;
    if (base >= nnz) return;
    long e = base + lane;
    int r = 0, c = 0; float w = 0.f;
    if (e < nnz) { r = rows[e]; c = cols[e]; w = vals[e]; }
    int jmax = (int)((nnz - base) < 64 ? (nnz - base) : 64);
    bool envHalf = lane >= 32;
    int  fi = lane & 31;                      // float2 index within the 64-feature half
#pragma unroll 1
    for (int j = 0; j < jmax; j++) {
        int   rj = __shfl(r, j, 64);
        int   cj = __shfl(c, j, 64);
        float wj = __shfl(w, j, 64);
        const float* binv = (cj < U) ? ui + (size_t)cj * 64 : ii + (size_t)(cj - U) * 64;
        const float* benv = (cj < U) ? ue + (size_t)cj * 64 : ie + (size_t)(cj - U) * 64;
        const float2* srow = (const float2*)(envHalf ? benv : binv);
        float2 x = srow[fi];
        float* d = dst + (size_t)rj * F2 + lane * 2;
        unsafeAtomicAdd(d,     x.x * wj);
        unsafeAtomicAdd(d + 1, x.y * wj);
    }
}

// Layer 2 (sparse output): only rows that are batch nodes accumulate, into
// compact curC [2B,128]. Source is layer-1 f32. ~2B/N of rows survive.
__global__ void spmm2_kernel(const int* __restrict__ rows, const int* __restrict__ cols,
                             const float* __restrict__ vals, const float* __restrict__ src,
                             const int* __restrict__ slots, float* __restrict__ dstC, long nnz) {
    long wid  = (long)(blockIdx.x * blockDim.x + threadIdx.x) >> 6;
    int lane = threadIdx.x & 63;
    long base = wid * 64;
    if (base >= nnz) return;
    long e = base + lane;
    int s = -1, c = 0; float w = 0.f;
    if (e < nnz) { s = slots[rows[e]]; c = cols[e]; w = vals[e]; }
    int jmax = (int)((nnz - base) < 64 ? (nnz - base) : 64);
#pragma unroll 1
    for (int j = 0; j < jmax; j++) {
        int sj = __shfl(s, j, 64);
        if (sj < 0) continue;                 // wave-uniform skip for non-batch rows
        int   cj = __shfl(c, j, 64);
        float wj = __shfl(w, j, 64);
        const float2* srow = (const float2*)(src + (size_t)cj * F2);
        float2 x = srow[lane];
        float* d = dstC + (size_t)sj * F2 + lane * 2;
        unsafeAtomicAdd(d,     x.x * wj);
        unsafeAtomicAdd(d + 1, x.y * wj);
    }
}

// Final: light = (x0 + A x0 + A^2 x0)/3 at batch nodes; scores + log_softmax.
// One wave per batch element; lane = feature (0..63). Output is f32:
// [inv_score(B) | env_aware(B) | env_outputs(B*E)].
__global__ void out_kernel(const int* __restrict__ users, const int* __restrict__ items,
                           const int* __restrict__ envs,
                           const float* __restrict__ ui, const float* __restrict__ ii,
                           const float* __restrict__ ue, const float* __restrict__ ie,
                           const float* __restrict__ cur1, const float* __restrict__ curC,
                           const int* __restrict__ slots,
                           const float* __restrict__ env_emb, const float* __restrict__ clfW,
                           const float* __restrict__ clfb, float* __restrict__ out,
                           int B, int U, int E) {
    long wid  = (long)(blockIdx.x * blockDim.x + threadIdx.x) >> 6;
    int lane = threadIdx.x & 63;
    if (wid >= B) return;
    int u   = users[wid];
    int itm = items[wid];
    int nit = U + itm;
    int ev  = envs[wid];
    int su = slots[u], si = slots[nit];
    size_t ub = (size_t)u * F2, ib = (size_t)nit * F2;
    size_t sub = (size_t)su * F2, sib = (size_t)si * F2;
    const float third = 1.f / 3.f;
    float ue_inv = (ui[(size_t)u * 64 + lane]   + cur1[ub + lane]      + curC[sub + lane])      * third;
    float ue_env = (ue[(size_t)u * 64 + lane]   + cur1[ub + 64 + lane] + curC[sub + 64 + lane]) * third;
    float ie_inv = (ii[(size_t)itm * 64 + lane] + cur1[ib + lane]      + curC[sib + lane])      * third;
    float ie_env = (ie[(size_t)itm * 64 + lane] + cur1[ib + 64 + lane] + curC[sib + 64 + lane]) * third;
    float eev  = env_emb[(size_t)ev * 64 + lane];
    float invp = ue_inv * ie_inv;
    float envp = ue_env * ie_env * eev;
    float s_inv = wsum(invp);
    float s_env = wsum(envp);
    float lg[EMAX];
    for (int e2 = 0; e2 < E; e2++)
        lg[e2] = wsum(invp * clfW[(size_t)e2 * 64 + lane]);
    if (lane == 0) {
        float inv_s = 1.f / (1.f + __expf(-s_inv));
        float env_m = 1.f / (1.f + __expf(-s_env));
        out[wid]     = inv_s;
        out[B + wid] = inv_s * env_m;
        float m = -1e30f;
        for (int e2 = 0; e2 < E; e2++) { lg[e2] += clfb[e2]; m = fmaxf(m, lg[e2]); }
        float se = 0.f;
        for (int e2 = 0; e2 < E; e2++) se += __expf(lg[e2] - m);
        float lse = m + __logf(se);
        float* eo = out + (size_t)2 * B + (size_t)wid * E;
        for (int e2 = 0; e2 < E; e2++) eo[e2] = lg[e2] - lse;
    }
}

extern "C" void kernel_launch(void* const* d_in, const int* in_sizes, int n_in,
                              void* d_out, int out_size, void* d_ws, size_t ws_size,
                              hipStream_t stream) {
    const int*   users    = (const int*)d_in[0];
    const int*   items    = (const int*)d_in[1];
    const int*   envs     = (const int*)d_in[2];
    // d_in[3] = alpha (f32, unused; ReverseLayerF is identity in forward)
    const int*   rows     = (const int*)d_in[4];
    const int*   cols     = (const int*)d_in[5];
    const float* vals     = (const float*)d_in[6];
    const float* user_inv = (const float*)d_in[7];
    const float* item_inv = (const float*)d_in[8];
    const float* user_env = (const float*)d_in[9];
    const float* item_env = (const float*)d_in[10];
    const float* env_emb  = (const float*)d_in[11];
    const float* clf_W    = (const float*)d_in[12];
    const float* clf_b    = (const float*)d_in[13];

    // Runtime dimensions derived from in_sizes (robust to harness rescaling).
    const int  B   = in_sizes[0];
    const long nnz = in_sizes[4];
    const int  U   = in_sizes[7] / FACTOR;
    const int  I   = in_sizes[8] / FACTOR;
    const int  E   = in_sizes[13] > EMAX ? EMAX : in_sizes[13];
    const int  N   = U + I;

    // ---- workspace layout (bytes) ----
    char* ws = (char*)d_ws;
    size_t cur1_bytes = (size_t)N * F2 * 4;
    size_t curc_bytes = (size_t)2 * B * F2 * 4;
    float* cur1f = (float*)ws;
    float* curC  = (float*)(ws + cur1_bytes);
    int*   slots = (int*)  (ws + cur1_bytes + curc_bytes);

    long n_cur1_f4 = (long)N * F2 / 4;
    long n_curc_f4 = (long)2 * B * F2 / 4;

    // zero accumulators, -1 the slot map (ws is poisoned 0xAA before every call)
    {
        long total = n_cur1_f4;
        int blocks = (int)((total + 255) / 256);
        if (blocks > 65535) blocks = 65535;
        init_kernel<<<blocks, 256, 0, stream>>>((float4*)cur1f, (float4*)curC, slots,
                                                n_cur1_f4, n_curc_f4, N);
    }

    build_slots_kernel<<<(2 * B + 255) / 256, 256, 0, stream>>>(users, items, slots, B, U);

    // layer 1: cur1 = A * x0  (dense, f32 atomic accumulate)
    long edge_waves = (nnz + 63) / 64;
    int  edge_blocks = (int)((edge_waves + 3) / 4);
    spmm1_kernel<<<edge_blocks, 256, 0, stream>>>(
        rows, cols, vals, user_inv, item_inv, user_env, item_env, cur1f, nnz, U);

    // layer 2: curC = (A * cur1) restricted to batch rows
    spmm2_kernel<<<edge_blocks, 256, 0, stream>>>(
        rows, cols, vals, cur1f, slots, curC, nnz);

    out_kernel<<<(int)(((long)B * 64 + 255) / 256), 256, 0, stream>>>(
        users, items, envs, user_inv, item_inv, user_env, item_env,
        cur1f, curC, slots, env_emb, clf_W, clf_b, (float*)d_out, B, U, E);
}

// Round 6
// 2370.655 us; speedup vs baseline: 3.6883x; 3.6883x over previous
//
#include <hip/hip_runtime.h>
#include <hip/hip_bf16.h>

// Feature dims fixed by the reference model architecture.
#define FACTOR   64
#define F2       128            // fused inv(64) + env(64) features
#define EMAX     8              // max supported env classes (reference: 4)

typedef __hip_bfloat162 bf162;

struct alignas(8) EdgeT { int c; float v; };

__device__ __forceinline__ float wsum(float x) {
#pragma unroll
    for (int o = 32; o > 0; o >>= 1) x += __shfl_xor(x, o, 64);
    return x;
}

// Zero the rowptr array [N+1].
__global__ void init_ptr_kernel(int* __restrict__ p, int M) {
    int t = blockIdx.x * blockDim.x + threadIdx.x;
    if (t < M) p[t] = 0;
}

// Histogram: p[r+1] += 1 for each edge row r.
__global__ void hist_kernel(const int* __restrict__ rows, int* __restrict__ p, long nnz) {
    long e = (long)blockIdx.x * blockDim.x + threadIdx.x;
    if (e < nnz) atomicAdd(&p[rows[e] + 1], 1);
}

// Single-block inclusive scan over p[0..M). After: p[r] = start of row r, p[N] = nnz.
__global__ void scan_kernel(int* __restrict__ p, int M) {
    __shared__ int wsums[4];
    int tid = threadIdx.x;
    int lane = tid & 63, wv = tid >> 6;
    int carry = 0;                       // uniform across threads
    for (int base = 0; base < M; base += 1024) {
        int idx = base + tid * 4;
        int v0 = (idx + 0 < M) ? p[idx + 0] : 0;
        int v1 = (idx + 1 < M) ? p[idx + 1] : 0;
        int v2 = (idx + 2 < M) ? p[idx + 2] : 0;
        int v3 = (idx + 3 < M) ? p[idx + 3] : 0;
        int s1 = v0 + v1 + v2 + v3;
        int s = s1;
#pragma unroll
        for (int o = 1; o < 64; o <<= 1) { int t = __shfl_up(s, o, 64); if (lane >= o) s += t; }
        if (lane == 63) wsums[wv] = s;
        __syncthreads();
        int woff = 0, total = 0;
#pragma unroll
        for (int i = 0; i < 4; i++) { int t = wsums[i]; if (i < wv) woff += t; total += t; }
        int run = carry + woff + (s - s1);          // exclusive prefix for this thread
        run += v0; if (idx + 0 < M) p[idx + 0] = run;
        run += v1; if (idx + 1 < M) p[idx + 1] = run;
        run += v2; if (idx + 2 < M) p[idx + 2] = run;
        run += v3; if (idx + 3 < M) p[idx + 3] = run;
        carry += total;
        __syncthreads();
    }
}

// Scatter edges into row-sorted order; bumps p[r] from start to end of row r.
// (After this, start of row r = (r==0) ? 0 : p[r-1].)
__global__ void scatter_kernel(const int* __restrict__ rows, const int* __restrict__ cols,
                               const float* __restrict__ vals, int* __restrict__ p,
                               EdgeT* __restrict__ edges, long nnz) {
    long e = (long)blockIdx.x * blockDim.x + threadIdx.x;
    if (e >= nnz) return;
    int pos = atomicAdd(&p[rows[e]], 1);
    EdgeT E; E.c = cols[e]; E.v = vals[e];
    edges[pos] = E;
}

// Layer 1 SpMM, CSR, one wave per row, register accumulate, bf16-packed store.
// Lane L<32: inv features (2L,2L+1); lane L>=32: env features (2(L-32), ...).
__global__ void spmm1_csr_kernel(const int* __restrict__ p, const EdgeT* __restrict__ edges,
                                 const float* __restrict__ ui, const float* __restrict__ ii,
                                 const float* __restrict__ ue, const float* __restrict__ ie,
                                 bf162* __restrict__ cur1h, int N, int U) {
    long wid = (long)(blockIdx.x * blockDim.x + threadIdx.x) >> 6;
    int lane = threadIdx.x & 63;
    if (wid >= N) return;
    int r = (int)wid;
    int start = (r == 0) ? 0 : p[r - 1];
    int end   = p[r];
    bool envHalf = lane >= 32;
    int  fi = lane & 31;
    float2 acc = {0.f, 0.f};
    for (int eb = start; eb < end; eb += 64) {
        int rem = end - eb; if (rem > 64) rem = 64;
        int c = 0; float v = 0.f;
        if (lane < rem) { EdgeT E = edges[eb + lane]; c = E.c; v = E.v; }
        for (int j = 0; j < rem; j++) {
            int   cj = __shfl(c, j, 64);
            float vj = __shfl(v, j, 64);
            const float* binv = (cj < U) ? ui + (size_t)cj * 64 : ii + (size_t)(cj - U) * 64;
            const float* benv = (cj < U) ? ue + (size_t)cj * 64 : ie + (size_t)(cj - U) * 64;
            const float2* srow = (const float2*)(envHalf ? benv : binv);
            float2 x = srow[fi];
            acc.x += x.x * vj;
            acc.y += x.y * vj;
        }
    }
    bf162 h;
    h.x = __float2bfloat16(acc.x);
    h.y = __float2bfloat16(acc.y);
    cur1h[(size_t)r * 64 + lane] = h;
}

// Layer 2 SpMM restricted to batch rows: slot w<B -> users[w], else U+items[w-B].
__global__ void spmm2_csr_kernel(const int* __restrict__ p, const EdgeT* __restrict__ edges,
                                 const int* __restrict__ users, const int* __restrict__ items,
                                 const bf162* __restrict__ cur1h, float2* __restrict__ curC,
                                 int B, int U) {
    long wid = (long)(blockIdx.x * blockDim.x + threadIdx.x) >> 6;
    int lane = threadIdx.x & 63;
    if (wid >= 2 * B) return;
    int node = (wid < B) ? users[wid] : U + items[wid - B];
    int start = (node == 0) ? 0 : p[node - 1];
    int end   = p[node];
    float2 acc = {0.f, 0.f};
    for (int eb = start; eb < end; eb += 64) {
        int rem = end - eb; if (rem > 64) rem = 64;
        int c = 0; float v = 0.f;
        if (lane < rem) { EdgeT E = edges[eb + lane]; c = E.c; v = E.v; }
        for (int j = 0; j < rem; j++) {
            int   cj = __shfl(c, j, 64);
            float vj = __shfl(v, j, 64);
            bf162 x = cur1h[(size_t)cj * 64 + lane];
            acc.x += __bfloat162float(x.x) * vj;
            acc.y += __bfloat162float(x.y) * vj;
        }
    }
    curC[(size_t)wid * 64 + lane] = acc;
}

// Final: light = (x0 + A x0 + A^2 x0)/3 at batch nodes; scores + log_softmax.
// One wave per batch element; lane = feature (0..63). Output f32:
// [inv_score(B) | env_aware(B) | env_outputs(B*E)].
__global__ void out_kernel(const int* __restrict__ users, const int* __restrict__ items,
                           const int* __restrict__ envs,
                           const float* __restrict__ ui, const float* __restrict__ ii,
                           const float* __restrict__ ue, const float* __restrict__ ie,
                           const __hip_bfloat16* __restrict__ cur1h, const float* __restrict__ curC,
                           const float* __restrict__ env_emb, const float* __restrict__ clfW,
                           const float* __restrict__ clfb, float* __restrict__ out,
                           int B, int U, int E) {
    long wid = (long)(blockIdx.x * blockDim.x + threadIdx.x) >> 6;
    int lane = threadIdx.x & 63;
    if (wid >= B) return;
    int u   = users[wid];
    int itm = items[wid];
    int nit = U + itm;
    int ev  = envs[wid];
    size_t ub = (size_t)u * F2, ib = (size_t)nit * F2;
    size_t sub = (size_t)wid * F2, sib = (size_t)(B + wid) * F2;
    const float third = 1.f / 3.f;
    float ue_inv = (ui[(size_t)u * 64 + lane]   + __bfloat162float(cur1h[ub + lane])      + curC[sub + lane])      * third;
    float ue_env = (ue[(size_t)u * 64 + lane]   + __bfloat162float(cur1h[ub + 64 + lane]) + curC[sub + 64 + lane]) * third;
    float ie_inv = (ii[(size_t)itm * 64 + lane] + __bfloat162float(cur1h[ib + lane])      + curC[sib + lane])      * third;
    float ie_env = (ie[(size_t)itm * 64 + lane] + __bfloat162float(cur1h[ib + 64 + lane]) + curC[sib + 64 + lane]) * third;
    float eev  = env_emb[(size_t)ev * 64 + lane];
    float invp = ue_inv * ie_inv;
    float envp = ue_env * ie_env * eev;
    float s_inv = wsum(invp);
    float s_env = wsum(envp);
    float lg[EMAX];
    for (int e2 = 0; e2 < E; e2++)
        lg[e2] = wsum(invp * clfW[(size_t)e2 * 64 + lane]);
    if (lane == 0) {
        float inv_s = 1.f / (1.f + __expf(-s_inv));
        float env_m = 1.f / (1.f + __expf(-s_env));
        out[wid]     = inv_s;
        out[B + wid] = inv_s * env_m;
        float m = -1e30f;
        for (int e2 = 0; e2 < E; e2++) { lg[e2] += clfb[e2]; m = fmaxf(m, lg[e2]); }
        float se = 0.f;
        for (int e2 = 0; e2 < E; e2++) se += __expf(lg[e2] - m);
        float lse = m + __logf(se);
        float* eo = out + (size_t)2 * B + (size_t)wid * E;
        for (int e2 = 0; e2 < E; e2++) eo[e2] = lg[e2] - lse;
    }
}

extern "C" void kernel_launch(void* const* d_in, const int* in_sizes, int n_in,
                              void* d_out, int out_size, void* d_ws, size_t ws_size,
                              hipStream_t stream) {
    const int*   users    = (const int*)d_in[0];
    const int*   items    = (const int*)d_in[1];
    const int*   envs     = (const int*)d_in[2];
    // d_in[3] = alpha (f32, unused; ReverseLayerF is identity in forward)
    const int*   rows     = (const int*)d_in[4];
    const int*   cols     = (const int*)d_in[5];
    const float* vals     = (const float*)d_in[6];
    const float* user_inv = (const float*)d_in[7];
    const float* item_inv = (const float*)d_in[8];
    const float* user_env = (const float*)d_in[9];
    const float* item_env = (const float*)d_in[10];
    const float* env_emb  = (const float*)d_in[11];
    const float* clf_W    = (const float*)d_in[12];
    const float* clf_b    = (const float*)d_in[13];

    // Runtime dimensions from in_sizes.
    const int  B   = in_sizes[0];
    const long nnz = in_sizes[4];
    const int  U   = in_sizes[7] / FACTOR;
    const int  I   = in_sizes[8] / FACTOR;
    const int  E   = in_sizes[13] > EMAX ? EMAX : in_sizes[13];
    const int  N   = U + I;

    // ---- workspace layout (8B-aligned), total ~171.6 MB at reference sizes ----
    char* ws = (char*)d_ws;
    EdgeT* edges = (EdgeT*)ws;                                   // nnz*8
    bf162* cur1h = (bf162*)(ws + (size_t)nnz * 8);               // N*64*4 = N*256
    float* curC  = (float*)(ws + (size_t)nnz * 8 + (size_t)N * 256);   // 2B*128*4
    int*   ptr   = (int*)  (ws + (size_t)nnz * 8 + (size_t)N * 256 + (size_t)2 * B * 512);

    // CSR build: zero ptr -> histogram -> inclusive scan -> scatter.
    init_ptr_kernel<<<(N + 1 + 255) / 256, 256, 0, stream>>>(ptr, N + 1);
    hist_kernel<<<(int)((nnz + 255) / 256), 256, 0, stream>>>(rows, ptr, nnz);
    scan_kernel<<<1, 256, 0, stream>>>(ptr, N + 1);
    scatter_kernel<<<(int)((nnz + 255) / 256), 256, 0, stream>>>(rows, cols, vals, ptr, edges, nnz);

    // Layer 1: cur1h = A * x0 (bf16-packed), one wave per row, no atomics.
    spmm1_csr_kernel<<<(int)(((long)N * 64 + 255) / 256), 256, 0, stream>>>(
        ptr, edges, user_inv, item_inv, user_env, item_env, cur1h, N, U);

    // Layer 2: curC = (A * cur1) at the 2B batch rows only.
    spmm2_csr_kernel<<<(int)(((long)2 * B * 64 + 255) / 256), 256, 0, stream>>>(
        ptr, edges, users, items, cur1h, (float2*)curC, B, U);

    out_kernel<<<(int)(((long)B * 64 + 255) / 256), 256, 0, stream>>>(
        users, items, envs, user_inv, item_inv, user_env, item_env,
        (const __hip_bfloat16*)cur1h, curC, env_emb, clf_W, clf_b, (float*)d_out, B, U, E);
}